// Round 3
// baseline (437.140 us; speedup 1.0000x reference)
//
#include <hip/hip_runtime.h>

// Problem constants
#define M_TOKENS 65536      // 8 * 8192
#define HID      256
#define KCODES   512

// Tiling
#define BM   128            // tokens per block
#define NC   128            // codes per chunk (4 chunks cover 512)
#define KS   32             // K step staged in LDS
#define PAD  33             // LDS row stride in floats (32 data + 1 pad)

#define IND_OFF  (M_TOKENS * HID)          // 16777216
#define LOSS_OFF (IND_OFF + M_TOKENS)      // 16842752

// Flag threshold: any token whose f32 top-2 gap is below this gets exact
// re-scoring with the emulated reference-f32 quantization pipeline.
// Must exceed 2*grid(3.05e-5) + f32 GEMM error (~1e-6). ~1.25% of tokens flag.
#define TAU      1.5e-4f

// ws layout: [0:8) double loss acc | [8:12) int flag count | [16:2064) c2[512]
//            | [4096:...) flag token list
#define WS_LIST_OFF 4096

// ---------------------------------------------------------------------------
// init: zero accumulators, precompute c2[k] = ||c_k||^2 (f64 -> f32)
// ---------------------------------------------------------------------------
__global__ void vq_init(const float* __restrict__ cb, float* __restrict__ c2,
                        double* __restrict__ acc, int* __restrict__ cnt) {
    int k = threadIdx.x;  // 512 threads, one per code
    if (k == 0) { *acc = 0.0; *cnt = 0; }
    const float* row = cb + k * HID;
    double s = 0.0;
    for (int i = 0; i < HID; ++i) {
        double v = (double)row[i];
        s = fma(v, v, s);
    }
    c2[k] = (float)s;
}

// ---------------------------------------------------------------------------
// main fused kernel: f32 cross-term GEMM + top-2 argmin + gather z_q + loss
// ---------------------------------------------------------------------------
__global__ __launch_bounds__(256, 2) void vq_main(
    const float* __restrict__ z, const float* __restrict__ cb,
    const float* __restrict__ c2g, float* __restrict__ out,
    double* __restrict__ loss_acc, int* __restrict__ cnt,
    int* __restrict__ list, int cap) {

    __shared__ float smem[(BM + NC) * PAD];   // 8448 floats = 33.8 KB
    float* zs = smem;                          // [BM][PAD]
    float* cs = smem + BM * PAD;               // [NC][PAD]

    const int tid = threadIdx.x;
    const int tx = tid & 15;    // code dim: 16 groups of 8 codes
    const int ty = tid >> 4;    // token dim: 16 groups of 8 tokens
    const int tokBase = blockIdx.x * BM;

    const float4* z4g  = reinterpret_cast<const float4*>(z);
    const float4* cb4g = reinterpret_cast<const float4*>(cb);

    float bs[8], bs2[8];
    int   bi[8];
    #pragma unroll
    for (int m = 0; m < 8; ++m) { bs[m] = 3.4e38f; bs2[m] = 3.4e38f; bi[m] = 0; }

    for (int chunk = 0; chunk < KCODES / NC; ++chunk) {
        float acc[8][8];
        #pragma unroll
        for (int m = 0; m < 8; ++m)
            #pragma unroll
            for (int n = 0; n < 8; ++n) acc[m][n] = 0.f;

        for (int ks = 0; ks < HID / KS; ++ks) {
            __syncthreads();
            #pragma unroll
            for (int i = 0; i < 4; ++i) {
                int f   = tid + i * 256;     // 0..1023
                int row = f >> 3;            // 0..127
                int k4  = f & 7;             // 0..7
                float4 zv = z4g[(tokBase + row) * (HID / 4) + ks * (KS / 4) + k4];
                int b = row * PAD + k4 * 4;
                zs[b + 0] = zv.x; zs[b + 1] = zv.y; zs[b + 2] = zv.z; zs[b + 3] = zv.w;
                float4 cv = cb4g[(chunk * NC + row) * (HID / 4) + ks * (KS / 4) + k4];
                cs[b + 0] = cv.x; cs[b + 1] = cv.y; cs[b + 2] = cv.z; cs[b + 3] = cv.w;
            }
            __syncthreads();

            #pragma unroll 2
            for (int k = 0; k < KS; ++k) {
                float zf[8], cf[8];
                #pragma unroll
                for (int m = 0; m < 8; ++m) zf[m] = zs[(ty * 8 + m) * PAD + k];
                #pragma unroll
                for (int n = 0; n < 8; ++n) cf[n] = cs[(tx * 8 + n) * PAD + k];
                #pragma unroll
                for (int m = 0; m < 8; ++m)
                    #pragma unroll
                    for (int n = 0; n < 8; ++n)
                        acc[m][n] = fmaf(zf[m], cf[n], acc[m][n]);
            }
        }

        // fold scores into per-token running top-2 (codes ascending per thread)
        #pragma unroll
        for (int n = 0; n < 8; ++n) {
            int code = chunk * NC + tx * 8 + n;
            float c2v = c2g[code];
            #pragma unroll
            for (int m = 0; m < 8; ++m) {
                float s = fmaf(-2.f, acc[m][n], c2v);  // c2 - 2*cross
                if (s < bs[m]) { bs2[m] = bs[m]; bs[m] = s; bi[m] = code; }
                else if (s < bs2[m]) bs2[m] = s;
            }
        }
    }

    // ---- cross-thread top-2 argmin reduction (reuse LDS) ----
    __syncthreads();
    float* rs   = smem;                                       // [BM][16]
    int*   ri   = reinterpret_cast<int*>(smem + BM * 16);     // [BM][16]
    float* rs2  = smem + BM * 32;                             // [BM][16]
    int*   inds = reinterpret_cast<int*>(smem + BM * 48);     // [BM]
    float* wred = smem + BM * 48 + BM;                        // [4]

    #pragma unroll
    for (int m = 0; m < 8; ++m) {
        int tok = ty * 8 + m;
        rs [tok * 16 + tx] = bs[m];
        ri [tok * 16 + tx] = bi[m];
        rs2[tok * 16 + tx] = bs2[m];
    }
    __syncthreads();

    if (tid < BM) {
        float B1 = rs[tid * 16];
        int   I1 = ri[tid * 16];
        float B2 = rs2[tid * 16];
        for (int j = 1; j < 16; ++j) {
            float b1 = rs [tid * 16 + j];
            int   i1 = ri [tid * 16 + j];
            float b2 = rs2[tid * 16 + j];
            if (b1 < B1 || (b1 == B1 && i1 < I1)) {
                B2 = fminf(B1, b2); B1 = b1; I1 = i1;
            } else {
                B2 = fminf(B2, b1);
            }
        }
        inds[tid] = I1;
        out[IND_OFF + tokBase + tid] = (float)I1;
        if (B2 - B1 <= TAU) {   // quantization could tie/reorder: exact recheck
            int pos = atomicAdd(cnt, 1);
            if (pos < cap) list[pos] = tokBase + tid;
        }
    }
    __syncthreads();

    // ---- gather z_q, write out, accumulate loss ----
    float loc = 0.f;
    float4* out4 = reinterpret_cast<float4*>(out);
    for (int it = 0; it < (BM * HID / 4) / 256; ++it) {   // 32 iters
        int e4  = it * 256 + tid;
        int tok = e4 >> 6;
        int h4  = e4 & 63;
        int code = inds[tok];
        float4 cv = cb4g[code * 64 + h4];
        float4 zv = z4g[(tokBase + tok) * 64 + h4];
        out4[(tokBase + tok) * 64 + h4] = cv;
        float dx = cv.x - zv.x, dy = cv.y - zv.y;
        float dz = cv.z - zv.z, dw = cv.w - zv.w;
        loc = fmaf(dx, dx, loc);
        loc = fmaf(dy, dy, loc);
        loc = fmaf(dz, dz, loc);
        loc = fmaf(dw, dw, loc);
    }
    #pragma unroll
    for (int off = 32; off > 0; off >>= 1) loc += __shfl_xor(loc, off, 64);
    int wave = tid >> 6;
    if ((tid & 63) == 0) wred[wave] = loc;
    __syncthreads();
    if (tid == 0) {
        double t = (double)wred[0] + (double)wred[1] +
                   (double)wred[2] + (double)wred[3];
        atomicAdd(loss_acc, t);
    }
}

// ---------------------------------------------------------------------------
// refine: re-score flagged tokens with the EMULATED reference f32 pipeline:
//   D_k = fl32( fl32(z2 - fl32(2*cross_k)) + c2_k ),  argmin first-index.
// cross computed in f64 (centers all plausible np accumulation orders).
// ---------------------------------------------------------------------------
__global__ __launch_bounds__(256) void vq_refine(
    const float* __restrict__ z, const float* __restrict__ cb,
    const float* __restrict__ c2g,
    const int* __restrict__ cnt, const int* __restrict__ list,
    float* __restrict__ out, int cap) {

    __shared__ float  zrow[HID];
    __shared__ double red_d[256];
    __shared__ int    red_i[256];

    const int tid = threadIdx.x;
    int n = *cnt; if (n > cap) n = cap;

    for (int idx = blockIdx.x; idx < n; idx += gridDim.x) {
        int t = list[idx];
        float zi = z[t * HID + tid];
        zrow[tid] = zi;
        red_d[tid] = (double)zi * (double)zi;
        __syncthreads();
        for (int s = 128; s > 0; s >>= 1) {
            if (tid < s) red_d[tid] += red_d[tid + s];
            __syncthreads();
        }
        float z2f = (float)red_d[0];     // binade-equivalent to numpy's z2
        __syncthreads();                  // protect red_d before reuse

        double bestD = 1e300; int bestK = 1 << 30;
        #pragma unroll
        for (int c = 0; c < 2; ++c) {
            int k = tid + c * 256;
            const float* cr = cb + k * HID;
            double acc = 0.0;
            for (int i = 0; i < HID; ++i)
                acc = fma((double)zrow[i], (double)cr[i], acc);
            float cross32 = (float)acc;                       // fl32(cross)
            float u = 2.0f * cross32;                          // fl32(2*cross) (exact)
            float tq = (float)((double)z2f - (double)u);       // fl32(z2 - u)
            double v = (double)tq + (double)c2g[k];
            float D = (float)v;                                // fl32(t + c2)
            double Dd = (double)D;
            if (Dd < bestD || (Dd == bestD && k < bestK)) { bestD = Dd; bestK = k; }
        }
        red_d[tid] = bestD; red_i[tid] = bestK;
        __syncthreads();
        for (int s = 128; s > 0; s >>= 1) {
            if (tid < s) {
                double d2 = red_d[tid + s]; int i2 = red_i[tid + s];
                if (d2 < red_d[tid] || (d2 == red_d[tid] && i2 < red_i[tid])) {
                    red_d[tid] = d2; red_i[tid] = i2;
                }
            }
            __syncthreads();
        }
        int best = red_i[0];
        if (tid == 0) out[IND_OFF + t] = (float)best;
        out[t * HID + tid] = cb[best * HID + tid];
        __syncthreads();   // protect zrow/red_* for next iteration
    }
}

// ---------------------------------------------------------------------------
// finalize: loss = 2 * mean((z_q - z)^2)
// ---------------------------------------------------------------------------
__global__ void vq_fin(const double* __restrict__ acc, float* __restrict__ out) {
    out[LOSS_OFF] = (float)(2.0 * (*acc) / (double)(M_TOKENS * HID));
}

extern "C" void kernel_launch(void* const* d_in, const int* in_sizes, int n_in,
                              void* d_out, int out_size, void* d_ws, size_t ws_size,
                              hipStream_t stream) {
    const float* z  = (const float*)d_in[0];
    const float* cb = (const float*)d_in[1];
    float* out = (float*)d_out;
    double* acc = (double*)d_ws;
    int*  cnt = (int*)((char*)d_ws + 8);
    float* c2 = (float*)((char*)d_ws + 16);
    int*  list = (int*)((char*)d_ws + WS_LIST_OFF);
    int cap = 0;
    if (ws_size > WS_LIST_OFF + 16) {
        size_t avail = (ws_size - WS_LIST_OFF) / 4;
        cap = (avail > 8192) ? 8192 : (int)avail;
    }

    vq_init<<<1, 512, 0, stream>>>(cb, c2, acc, cnt);
    vq_main<<<M_TOKENS / BM, 256, 0, stream>>>(z, cb, c2, out, acc, cnt, list, cap);
    vq_refine<<<256, 256, 0, stream>>>(z, cb, c2, cnt, list, out, cap);
    vq_fin<<<1, 1, 0, stream>>>(acc, out);
}

// Round 4
// 231.820 us; speedup vs baseline: 1.8857x; 1.8857x over previous
//
#include <hip/hip_runtime.h>

// Problem constants
#define M_TOKENS 65536      // 8 * 8192
#define HID      256
#define KCODES   512

#define IND_OFF  (M_TOKENS * HID)          // 16777216
#define LOSS_OFF (IND_OFF + M_TOKENS)      // 16842752

// Flag threshold: any token whose top-2 score gap is below this gets exact
// re-scoring with the emulated reference-f32 quantization pipeline.
// bf16-split GEMM worst-case score error ~5e-6 << TAU; grid 2*3.05e-5 < TAU.
#define TAU      1.5e-4f

// ws layout (fast path):
//   [0:8) double loss | [8:12) int cnt | [16:2064) c2[512]
//   [4096 : +256K) B_hi fragments | [266240 : +256K) B_lo | [528384 : +32K) list
#define WS_C2_OFF        16
#define WS_BHI_OFF       4096
#define WS_BLO_OFF       (4096 + 262144)
#define WS_LIST_OFF_FAST (4096 + 524288)
#define WS_LIST_OFF_SLOW 4096
#define WS_MIN_FAST      (WS_LIST_OFF_FAST + 8192 * 4)

typedef __attribute__((ext_vector_type(8))) short  short8;   // 8 bf16
typedef __attribute__((ext_vector_type(4))) float  f32x4;

__device__ inline unsigned short f2bf(float f) {             // RNE f32->bf16
    unsigned u = __float_as_uint(f);
    u += 0x7FFF + ((u >> 16) & 1);
    return (unsigned short)(u >> 16);
}
__device__ inline float bf2f(unsigned short h) {
    return __uint_as_float(((unsigned)h) << 16);
}

// ---------------------------------------------------------------------------
// init: zero accumulators, precompute c2[k] = ||c_k||^2 (f64 -> f32)
// ---------------------------------------------------------------------------
__global__ void vq_init(const float* __restrict__ cb, float* __restrict__ c2,
                        double* __restrict__ acc, int* __restrict__ cnt) {
    int k = threadIdx.x;  // 512 threads, one per code
    if (k == 0) { *acc = 0.0; *cnt = 0; }
    const float* row = cb + k * HID;
    double s = 0.0;
    for (int i = 0; i < HID; ++i) {
        double v = (double)row[i];
        s = fma(v, v, s);
    }
    c2[k] = (float)s;
}

// ---------------------------------------------------------------------------
// prepB: pre-swizzle codebook into MFMA B-fragment lane order, bf16 hi/lo.
// Fragment (nb, kb): lane l, elem j -> code = nb*16 + (l&15),
//                                      k = kb*32 + (l>>4)*8 + j.
// Stored at (frag*64 + lane)*8 shorts; one short8 per (frag,lane).
// ---------------------------------------------------------------------------
__global__ __launch_bounds__(256) void vq_prepB(
    const float* __restrict__ cb,
    unsigned short* __restrict__ Bhi, unsigned short* __restrict__ Blo) {
    int g = blockIdx.x * 256 + threadIdx.x;   // 0..16383 = frag*64 + lane
    int frag = g >> 6, lane = g & 63;
    int nb = frag >> 3, kb = frag & 7;
    int code = nb * 16 + (lane & 15);
    int kk = kb * 32 + (lane >> 4) * 8;
    const float4* s4 = reinterpret_cast<const float4*>(cb + code * HID + kk);
    float4 v0 = s4[0], v1 = s4[1];
    float f[8] = {v0.x, v0.y, v0.z, v0.w, v1.x, v1.y, v1.z, v1.w};
    short8 vh, vl;
    #pragma unroll
    for (int j = 0; j < 8; ++j) {
        unsigned short h = f2bf(f[j]);
        vh[j] = (short)h;
        vl[j] = (short)f2bf(f[j] - bf2f(h));
    }
    *reinterpret_cast<short8*>(Bhi + (size_t)g * 8) = vh;
    *reinterpret_cast<short8*>(Blo + (size_t)g * 8) = vl;
}

// ---------------------------------------------------------------------------
// main MFMA kernel: bf16-split cross-term + top-2 argmin + gather + loss.
// 512 threads = 8 waves; wave owns 32 tokens (2 M-fragments of 16).
// Grid = 256 blocks = 1 block/CU (VGPR-forced). No LDS.
// ---------------------------------------------------------------------------
__global__ __launch_bounds__(512, 2) void vq_main_mfma(
    const float* __restrict__ z, const float* __restrict__ cb,
    const float* __restrict__ c2g,
    const unsigned short* __restrict__ Bhi,
    const unsigned short* __restrict__ Blo,
    float* __restrict__ out, double* __restrict__ loss_acc,
    int* __restrict__ cnt, int* __restrict__ list, int cap) {

    const int tid  = threadIdx.x;
    const int wid  = tid >> 6;
    const int lane = tid & 63;
    const int tokW = blockIdx.x * 256 + wid * 32;   // wave's first token

    const float4* z4  = reinterpret_cast<const float4*>(z);
    const float4* cb4 = reinterpret_cast<const float4*>(cb);
    const short8* bh8 = reinterpret_cast<const short8*>(Bhi);
    const short8* bl8 = reinterpret_cast<const short8*>(Blo);

    // ---- load this wave's z rows as A fragments (bf16 hi/lo, registers) ----
    // A frag (mf, kb): lane holds token tokW+mf*16+(l&15), k = kb*32+(l>>4)*8+j
    short8 ah[2][8], al[2][8];
    #pragma unroll
    for (int mf = 0; mf < 2; ++mf) {
        int token = tokW + mf * 16 + (lane & 15);
        const float4* zr = z4 + (size_t)token * 64 + (lane >> 4) * 2;
        #pragma unroll
        for (int kb = 0; kb < 8; ++kb) {
            float4 v0 = zr[kb * 8];
            float4 v1 = zr[kb * 8 + 1];
            float f[8] = {v0.x, v0.y, v0.z, v0.w, v1.x, v1.y, v1.z, v1.w};
            short8 vh, vl;
            #pragma unroll
            for (int j = 0; j < 8; ++j) {
                unsigned short h = f2bf(f[j]);
                vh[j] = (short)h;
                vl[j] = (short)f2bf(f[j] - bf2f(h));
            }
            ah[mf][kb] = vh;
            al[mf][kb] = vl;
        }
    }

    // per-lane running top-2 for 8 (mf, r) token slots
    float b1[2][4], b2[2][4];
    int   i1[2][4];
    #pragma unroll
    for (int mf = 0; mf < 2; ++mf)
        #pragma unroll
        for (int r = 0; r < 4; ++r) { b1[mf][r] = 3.4e38f; b2[mf][r] = 3.4e38f; i1[mf][r] = 0; }

    // ---- main loop over 32 code-chunks of 16 ----
    for (int nb = 0; nb < 32; ++nb) {
        __syncthreads();   // keep 8 waves in lockstep so L1 serves B for all
        f32x4 acc0 = {0.f, 0.f, 0.f, 0.f};
        f32x4 acc1 = {0.f, 0.f, 0.f, 0.f};
        #pragma unroll
        for (int kb = 0; kb < 8; ++kb) {
            short8 vbh = bh8[(nb * 8 + kb) * 64 + lane];
            short8 vbl = bl8[(nb * 8 + kb) * 64 + lane];
            acc0 = __builtin_amdgcn_mfma_f32_16x16x32_bf16(ah[0][kb], vbh, acc0, 0, 0, 0);
            acc1 = __builtin_amdgcn_mfma_f32_16x16x32_bf16(ah[1][kb], vbh, acc1, 0, 0, 0);
            acc0 = __builtin_amdgcn_mfma_f32_16x16x32_bf16(al[0][kb], vbh, acc0, 0, 0, 0);
            acc1 = __builtin_amdgcn_mfma_f32_16x16x32_bf16(al[1][kb], vbh, acc1, 0, 0, 0);
            acc0 = __builtin_amdgcn_mfma_f32_16x16x32_bf16(ah[0][kb], vbl, acc0, 0, 0, 0);
            acc1 = __builtin_amdgcn_mfma_f32_16x16x32_bf16(ah[1][kb], vbl, acc1, 0, 0, 0);
        }
        int code = nb * 16 + (lane & 15);
        float c2v = c2g[code];
        #pragma unroll
        for (int r = 0; r < 4; ++r) {
            float s0 = fmaf(-2.f, acc0[r], c2v);   // c2 - 2*cross
            if (s0 < b1[0][r]) { b2[0][r] = b1[0][r]; b1[0][r] = s0; i1[0][r] = code; }
            else if (s0 < b2[0][r]) b2[0][r] = s0;
            float s1 = fmaf(-2.f, acc1[r], c2v);
            if (s1 < b1[1][r]) { b2[1][r] = b1[1][r]; b1[1][r] = s1; i1[1][r] = code; }
            else if (s1 < b2[1][r]) b2[1][r] = s1;
        }
    }

    // ---- merge top-2 across the 16 lanes of each quadrant group ----
    #pragma unroll
    for (int st = 1; st <= 8; st <<= 1) {
        #pragma unroll
        for (int mf = 0; mf < 2; ++mf)
            #pragma unroll
            for (int r = 0; r < 4; ++r) {
                float ob1 = __shfl_xor(b1[mf][r], st, 64);
                int   oi1 = __shfl_xor(i1[mf][r], st, 64);
                float ob2 = __shfl_xor(b2[mf][r], st, 64);
                if (ob1 < b1[mf][r] || (ob1 == b1[mf][r] && oi1 < i1[mf][r])) {
                    b2[mf][r] = fminf(b1[mf][r], ob2);
                    b1[mf][r] = ob1;
                    i1[mf][r] = oi1;
                } else {
                    b2[mf][r] = fminf(b2[mf][r], ob1);
                }
            }
    }

    // ---- write indices + flag ambiguous tokens ----
    if ((lane & 15) == 0) {
        int q = lane >> 4;
        #pragma unroll
        for (int mf = 0; mf < 2; ++mf)
            #pragma unroll
            for (int r = 0; r < 4; ++r) {
                int tok = tokW + mf * 16 + q * 4 + r;
                out[IND_OFF + tok] = (float)i1[mf][r];
                if (b2[mf][r] - b1[mf][r] <= TAU) {
                    int pos = atomicAdd(cnt, 1);
                    if (pos < cap) list[pos] = tok;
                }
            }
    }

    // ---- gather z_q, write out, accumulate loss ----
    float loc = 0.f;
    float4* out4 = reinterpret_cast<float4*>(out);
    #pragma unroll
    for (int tt = 0; tt < 32; ++tt) {
        int code = __shfl(i1[tt >> 4][tt & 3], ((tt >> 2) & 3) * 16, 64);
        int tok = tokW + tt;
        float4 cv = cb4[(size_t)code * 64 + lane];
        float4 zv = z4[(size_t)tok * 64 + lane];
        out4[(size_t)tok * 64 + lane] = cv;
        float dx = cv.x - zv.x, dy = cv.y - zv.y;
        float dz = cv.z - zv.z, dw = cv.w - zv.w;
        loc = fmaf(dx, dx, loc);
        loc = fmaf(dy, dy, loc);
        loc = fmaf(dz, dz, loc);
        loc = fmaf(dw, dw, loc);
    }
    #pragma unroll
    for (int off = 32; off > 0; off >>= 1) loc += __shfl_xor(loc, off, 64);
    if (lane == 0) atomicAdd(loss_acc, (double)loc);
}

// ---------------------------------------------------------------------------
// FALLBACK (small ws): round-3 f32 VALU kernel, verified correct.
// ---------------------------------------------------------------------------
#define BM   128
#define NC   128
#define KS   32
#define PAD  33

__global__ __launch_bounds__(256, 2) void vq_main_f32(
    const float* __restrict__ z, const float* __restrict__ cb,
    const float* __restrict__ c2g, float* __restrict__ out,
    double* __restrict__ loss_acc, int* __restrict__ cnt,
    int* __restrict__ list, int cap) {

    __shared__ float smem[(BM + NC) * PAD];
    float* zs = smem;
    float* cs = smem + BM * PAD;

    const int tid = threadIdx.x;
    const int tx = tid & 15;
    const int ty = tid >> 4;
    const int tokBase = blockIdx.x * BM;

    const float4* z4g  = reinterpret_cast<const float4*>(z);
    const float4* cb4g = reinterpret_cast<const float4*>(cb);

    float bs[8], bs2[8];
    int   bi[8];
    #pragma unroll
    for (int m = 0; m < 8; ++m) { bs[m] = 3.4e38f; bs2[m] = 3.4e38f; bi[m] = 0; }

    for (int chunk = 0; chunk < KCODES / NC; ++chunk) {
        float acc[8][8];
        #pragma unroll
        for (int m = 0; m < 8; ++m)
            #pragma unroll
            for (int n = 0; n < 8; ++n) acc[m][n] = 0.f;

        for (int ks = 0; ks < HID / KS; ++ks) {
            __syncthreads();
            #pragma unroll
            for (int i = 0; i < 4; ++i) {
                int f   = tid + i * 256;
                int row = f >> 3;
                int k4  = f & 7;
                float4 zv = z4g[(tokBase + row) * (HID / 4) + ks * (KS / 4) + k4];
                int b = row * PAD + k4 * 4;
                zs[b + 0] = zv.x; zs[b + 1] = zv.y; zs[b + 2] = zv.z; zs[b + 3] = zv.w;
                float4 cv = cb4g[(chunk * NC + row) * (HID / 4) + ks * (KS / 4) + k4];
                cs[b + 0] = cv.x; cs[b + 1] = cv.y; cs[b + 2] = cv.z; cs[b + 3] = cv.w;
            }
            __syncthreads();

            #pragma unroll 2
            for (int k = 0; k < KS; ++k) {
                float zf[8], cf[8];
                #pragma unroll
                for (int m = 0; m < 8; ++m) zf[m] = zs[(ty * 8 + m) * PAD + k];
                #pragma unroll
                for (int n = 0; n < 8; ++n) cf[n] = cs[(tx * 8 + n) * PAD + k];
                #pragma unroll
                for (int m = 0; m < 8; ++m)
                    #pragma unroll
                    for (int n = 0; n < 8; ++n)
                        acc[m][n] = fmaf(zf[m], cf[n], acc[m][n]);
            }
        }

        #pragma unroll
        for (int n = 0; n < 8; ++n) {
            int code = chunk * NC + tx * 8 + n;
            float c2v = c2g[code];
            #pragma unroll
            for (int m = 0; m < 8; ++m) {
                float s = fmaf(-2.f, acc[m][n], c2v);
                if (s < bs[m]) { bs2[m] = bs[m]; bs[m] = s; bi[m] = code; }
                else if (s < bs2[m]) bs2[m] = s;
            }
        }
    }

    __syncthreads();
    float* rs   = smem;
    int*   ri   = reinterpret_cast<int*>(smem + BM * 16);
    float* rs2  = smem + BM * 32;
    int*   inds = reinterpret_cast<int*>(smem + BM * 48);
    float* wred = smem + BM * 48 + BM;

    #pragma unroll
    for (int m = 0; m < 8; ++m) {
        int tok = ty * 8 + m;
        rs [tok * 16 + tx] = bs[m];
        ri [tok * 16 + tx] = bi[m];
        rs2[tok * 16 + tx] = bs2[m];
    }
    __syncthreads();

    if (tid < BM) {
        float B1 = rs[tid * 16];
        int   I1 = ri[tid * 16];
        float B2 = rs2[tid * 16];
        for (int j = 1; j < 16; ++j) {
            float b1v = rs [tid * 16 + j];
            int   i1v = ri [tid * 16 + j];
            float b2v = rs2[tid * 16 + j];
            if (b1v < B1 || (b1v == B1 && i1v < I1)) {
                B2 = fminf(B1, b2v); B1 = b1v; I1 = i1v;
            } else {
                B2 = fminf(B2, b1v);
            }
        }
        inds[tid] = I1;
        out[IND_OFF + tokBase + tid] = (float)I1;
        if (B2 - B1 <= TAU) {
            int pos = atomicAdd(cnt, 1);
            if (pos < cap) list[pos] = tokBase + tid;
        }
    }
    __syncthreads();

    float loc = 0.f;
    float4* out4 = reinterpret_cast<float4*>(out);
    for (int it = 0; it < (BM * HID / 4) / 256; ++it) {
        int e4  = it * 256 + tid;
        int tok = e4 >> 6;
        int h4  = e4 & 63;
        int code = inds[tok];
        float4 cv = cb4g[code * 64 + h4];
        float4 zv = z4g[(tokBase + tok) * 64 + h4];
        out4[(tokBase + tok) * 64 + h4] = cv;
        float dx = cv.x - zv.x, dy = cv.y - zv.y;
        float dz = cv.z - zv.z, dw = cv.w - zv.w;
        loc = fmaf(dx, dx, loc);
        loc = fmaf(dy, dy, loc);
        loc = fmaf(dz, dz, loc);
        loc = fmaf(dw, dw, loc);
    }
    #pragma unroll
    for (int off = 32; off > 0; off >>= 1) loc += __shfl_xor(loc, off, 64);
    int wave = tid >> 6;
    if ((tid & 63) == 0) wred[wave] = loc;
    __syncthreads();
    if (tid == 0) {
        double t = (double)wred[0] + (double)wred[1] +
                   (double)wred[2] + (double)wred[3];
        atomicAdd(loss_acc, t);
    }
}

// ---------------------------------------------------------------------------
// refine: re-score flagged tokens with the EMULATED reference f32 pipeline:
//   D_k = fl32( fl32(z2 - fl32(2*cross_k)) + c2_k ),  argmin first-index.
// ---------------------------------------------------------------------------
__global__ __launch_bounds__(256) void vq_refine(
    const float* __restrict__ z, const float* __restrict__ cb,
    const float* __restrict__ c2g,
    const int* __restrict__ cnt, const int* __restrict__ list,
    float* __restrict__ out, int cap) {

    __shared__ float  zrow[HID];
    __shared__ double red_d[256];
    __shared__ int    red_i[256];

    const int tid = threadIdx.x;
    int n = *cnt; if (n > cap) n = cap;

    for (int idx = blockIdx.x; idx < n; idx += gridDim.x) {
        int t = list[idx];
        float zi = z[t * HID + tid];
        zrow[tid] = zi;
        red_d[tid] = (double)zi * (double)zi;
        __syncthreads();
        for (int s = 128; s > 0; s >>= 1) {
            if (tid < s) red_d[tid] += red_d[tid + s];
            __syncthreads();
        }
        float z2f = (float)red_d[0];
        __syncthreads();

        double bestD = 1e300; int bestK = 1 << 30;
        #pragma unroll
        for (int c = 0; c < 2; ++c) {
            int k = tid + c * 256;
            const float* cr = cb + k * HID;
            double acc = 0.0;
            for (int i = 0; i < HID; ++i)
                acc = fma((double)zrow[i], (double)cr[i], acc);
            float cross32 = (float)acc;
            float u = 2.0f * cross32;
            float tq = (float)((double)z2f - (double)u);
            double v = (double)tq + (double)c2g[k];
            float D = (float)v;
            double Dd = (double)D;
            if (Dd < bestD || (Dd == bestD && k < bestK)) { bestD = Dd; bestK = k; }
        }
        red_d[tid] = bestD; red_i[tid] = bestK;
        __syncthreads();
        for (int s = 128; s > 0; s >>= 1) {
            if (tid < s) {
                double d2 = red_d[tid + s]; int i2 = red_i[tid + s];
                if (d2 < red_d[tid] || (d2 == red_d[tid] && i2 < red_i[tid])) {
                    red_d[tid] = d2; red_i[tid] = i2;
                }
            }
            __syncthreads();
        }
        int best = red_i[0];
        if (tid == 0) out[IND_OFF + t] = (float)best;
        out[t * HID + tid] = cb[best * HID + tid];
        __syncthreads();
    }
}

// ---------------------------------------------------------------------------
// finalize: loss = 2 * mean((z_q - z)^2)
// ---------------------------------------------------------------------------
__global__ void vq_fin(const double* __restrict__ acc, float* __restrict__ out) {
    out[LOSS_OFF] = (float)(2.0 * (*acc) / (double)(M_TOKENS * HID));
}

extern "C" void kernel_launch(void* const* d_in, const int* in_sizes, int n_in,
                              void* d_out, int out_size, void* d_ws, size_t ws_size,
                              hipStream_t stream) {
    const float* z  = (const float*)d_in[0];
    const float* cb = (const float*)d_in[1];
    float* out = (float*)d_out;
    double* acc = (double*)d_ws;
    int*  cnt = (int*)((char*)d_ws + 8);
    float* c2 = (float*)((char*)d_ws + WS_C2_OFF);

    vq_init<<<1, 512, 0, stream>>>(cb, c2, acc, cnt);

    if (ws_size >= WS_MIN_FAST) {
        unsigned short* Bhi = (unsigned short*)((char*)d_ws + WS_BHI_OFF);
        unsigned short* Blo = (unsigned short*)((char*)d_ws + WS_BLO_OFF);
        int* list = (int*)((char*)d_ws + WS_LIST_OFF_FAST);
        int cap = 8192;
        vq_prepB<<<64, 256, 0, stream>>>(cb, Bhi, Blo);
        vq_main_mfma<<<M_TOKENS / 256, 512, 0, stream>>>(
            z, cb, c2, Bhi, Blo, out, acc, cnt, list, cap);
        vq_refine<<<256, 256, 0, stream>>>(z, cb, c2, cnt, list, out, cap);
    } else {
        int* list = (int*)((char*)d_ws + WS_LIST_OFF_SLOW);
        int cap = 0;
        if (ws_size > WS_LIST_OFF_SLOW + 16) {
            size_t avail = (ws_size - WS_LIST_OFF_SLOW) / 4;
            cap = (avail > 8192) ? 8192 : (int)avail;
        }
        vq_main_f32<<<M_TOKENS / BM, 256, 0, stream>>>(
            z, cb, c2, out, acc, cnt, list, cap);
        vq_refine<<<256, 256, 0, stream>>>(z, cb, c2, cnt, list, out, cap);
    }
    vq_fin<<<1, 1, 0, stream>>>(acc, out);
}

// Round 5
// 230.547 us; speedup vs baseline: 1.8961x; 1.0055x over previous
//
#include <hip/hip_runtime.h>

// Problem constants
#define M_TOKENS 65536      // 8 * 8192
#define HID      256
#define KCODES   512

#define IND_OFF  (M_TOKENS * HID)          // 16777216
#define LOSS_OFF (IND_OFF + M_TOKENS)      // 16842752

// Flag threshold: any token whose top-2 score gap is below this gets exact
// re-scoring with the emulated reference-f32 quantization pipeline.
// bf16-split GEMM worst-case score error ~5e-6 << TAU; grid 2*3.05e-5 < TAU.
#define TAU      1.5e-4f

// ws layout (fast path):
//   [0:8) double loss | [8:12) int cnt | [16:2064) c2[512]
//   [4096 : +256K) B_hi fragments | [266240 : +256K) B_lo | [528384 : +32K) list
#define WS_C2_OFF        16
#define WS_BHI_OFF       4096
#define WS_BLO_OFF       (4096 + 262144)
#define WS_LIST_OFF_FAST (4096 + 524288)
#define WS_LIST_OFF_SLOW 4096
#define WS_MIN_FAST      (WS_LIST_OFF_FAST + 8192 * 4)

typedef __attribute__((ext_vector_type(8))) short  short8;   // 8 bf16
typedef __attribute__((ext_vector_type(4))) float  f32x4;

__device__ inline unsigned short f2bf(float f) {             // RNE f32->bf16
    unsigned u = __float_as_uint(f);
    u += 0x7FFF + ((u >> 16) & 1);
    return (unsigned short)(u >> 16);
}
__device__ inline float bf2f(unsigned short h) {
    return __uint_as_float(((unsigned)h) << 16);
}

// ---------------------------------------------------------------------------
// prep: blocks 0..63 swizzle codebook into MFMA B-fragment order (bf16 hi/lo);
//       blocks 64..65 compute c2[k] (f64) and zero the accumulators.
// Fragment (nb, kb): lane l, elem j -> code = nb*16 + (l&15),
//                                      k = kb*32 + (l>>4)*8 + j.
// ---------------------------------------------------------------------------
__global__ __launch_bounds__(256) void vq_prep(
    const float* __restrict__ cb,
    unsigned short* __restrict__ Bhi, unsigned short* __restrict__ Blo,
    float* __restrict__ c2, double* __restrict__ acc, int* __restrict__ cnt) {
    int b = blockIdx.x;
    if (b < 64) {
        int g = b * 256 + threadIdx.x;   // 0..16383 = frag*64 + lane
        int frag = g >> 6, lane = g & 63;
        int nb = frag >> 3, kb = frag & 7;
        int code = nb * 16 + (lane & 15);
        int kk = kb * 32 + (lane >> 4) * 8;
        const float4* s4 = reinterpret_cast<const float4*>(cb + code * HID + kk);
        float4 v0 = s4[0], v1 = s4[1];
        float f[8] = {v0.x, v0.y, v0.z, v0.w, v1.x, v1.y, v1.z, v1.w};
        short8 vh, vl;
        #pragma unroll
        for (int j = 0; j < 8; ++j) {
            unsigned short h = f2bf(f[j]);
            vh[j] = (short)h;
            vl[j] = (short)f2bf(f[j] - bf2f(h));
        }
        *reinterpret_cast<short8*>(Bhi + (size_t)g * 8) = vh;
        *reinterpret_cast<short8*>(Blo + (size_t)g * 8) = vl;
    } else {
        if (b == 64 && threadIdx.x == 0) { *acc = 0.0; *cnt = 0; }
        int k = (b - 64) * 256 + threadIdx.x;   // 0..511
        const float* row = cb + k * HID;
        double s = 0.0;
        for (int i = 0; i < HID; ++i) {
            double v = (double)row[i];
            s = fma(v, v, s);
        }
        c2[k] = (float)s;
    }
}

// ---------------------------------------------------------------------------
// main MFMA kernel: bf16-split cross-term + top-2 argmin + gather + loss.
// 256 threads = 4 waves; wave owns 16 tokens (1 M-fragment). Grid = 1024
// blocks -> 4 blocks/CU, 16 waves/CU (VGPR<=128). Loss computed
// algebraically: ||zq-z||^2 = z2 + (c2_best - 2 cross_best) -- no z re-read.
// ---------------------------------------------------------------------------
__global__ __launch_bounds__(256, 4) void vq_main_mfma(
    const float* __restrict__ z, const float* __restrict__ cb,
    const float* __restrict__ c2g,
    const unsigned short* __restrict__ Bhi,
    const unsigned short* __restrict__ Blo,
    float* __restrict__ out, double* __restrict__ loss_acc,
    int* __restrict__ cnt, int* __restrict__ list, int cap) {

    const int tid  = threadIdx.x;
    const int wid  = tid >> 6;
    const int lane = tid & 63;
    const int q    = lane >> 4;
    const int tokW = blockIdx.x * 64 + wid * 16;   // wave's first token

    const float4* z4  = reinterpret_cast<const float4*>(z);
    const float4* cb4 = reinterpret_cast<const float4*>(cb);
    const short8* bh8 = reinterpret_cast<const short8*>(Bhi);
    const short8* bl8 = reinterpret_cast<const short8*>(Blo);

    // ---- load wave's 16 z rows as A fragments (bf16 hi/lo) + z2 partials ----
    // A frag kb: lane holds token tokW+(l&15), k = kb*32+(l>>4)*8+j
    short8 ah[8], al[8];
    float sq = 0.f;
    {
        int token = tokW + (lane & 15);
        const float4* zr = z4 + (size_t)token * 64 + q * 2;
        #pragma unroll
        for (int kb = 0; kb < 8; ++kb) {
            float4 v0 = zr[kb * 8];
            float4 v1 = zr[kb * 8 + 1];
            float f[8] = {v0.x, v0.y, v0.z, v0.w, v1.x, v1.y, v1.z, v1.w};
            short8 vh, vl;
            #pragma unroll
            for (int j = 0; j < 8; ++j) {
                unsigned short h = f2bf(f[j]);
                vh[j] = (short)h;
                vl[j] = (short)f2bf(f[j] - bf2f(h));
                sq = fmaf(f[j], f[j], sq);
            }
            ah[kb] = vh;
            al[kb] = vl;
        }
    }
    // z2 of token tokW+(lane&15), replicated on all 4 q-groups
    sq += __shfl_xor(sq, 16, 64);
    sq += __shfl_xor(sq, 32, 64);

    // per-lane running top-2 for 4 token slots (rows q*4+r)
    float b1[4], b2[4];
    int   i1[4];
    #pragma unroll
    for (int r = 0; r < 4; ++r) { b1[r] = 3.4e38f; b2[r] = 3.4e38f; i1[r] = 0; }

    // ---- main loop over 32 code-chunks of 16 ----
    for (int nb = 0; nb < 32; ++nb) {
        __syncthreads();   // keep waves in lockstep so L1 serves B for all
        f32x4 acc = {0.f, 0.f, 0.f, 0.f};
        #pragma unroll
        for (int kb = 0; kb < 8; ++kb) {
            short8 vbh = bh8[(nb * 8 + kb) * 64 + lane];
            short8 vbl = bl8[(nb * 8 + kb) * 64 + lane];
            acc = __builtin_amdgcn_mfma_f32_16x16x32_bf16(ah[kb], vbh, acc, 0, 0, 0);
            acc = __builtin_amdgcn_mfma_f32_16x16x32_bf16(al[kb], vbh, acc, 0, 0, 0);
            acc = __builtin_amdgcn_mfma_f32_16x16x32_bf16(ah[kb], vbl, acc, 0, 0, 0);
        }
        int code = nb * 16 + (lane & 15);
        float c2v = c2g[code];
        #pragma unroll
        for (int r = 0; r < 4; ++r) {
            float s = fmaf(-2.f, acc[r], c2v);   // c2 - 2*cross
            if (s < b1[r]) { b2[r] = b1[r]; b1[r] = s; i1[r] = code; }
            else if (s < b2[r]) b2[r] = s;
        }
    }

    // ---- merge top-2 across the 16 lanes of each row group ----
    #pragma unroll
    for (int st = 1; st <= 8; st <<= 1) {
        #pragma unroll
        for (int r = 0; r < 4; ++r) {
            float ob1 = __shfl_xor(b1[r], st, 64);
            int   oi1 = __shfl_xor(i1[r], st, 64);
            float ob2 = __shfl_xor(b2[r], st, 64);
            if (ob1 < b1[r] || (ob1 == b1[r] && oi1 < i1[r])) {
                b2[r] = fminf(b1[r], ob2);
                b1[r] = ob1;
                i1[r] = oi1;
            } else {
                b2[r] = fminf(b2[r], ob1);
            }
        }
    }

    // ---- indices (float4 per lane-group) + ambiguity flags + loss ----
    if ((lane & 15) == 0) {
        float4 iv;
        #pragma unroll
        for (int r = 0; r < 4; ++r) {
            ((float*)&iv)[r] = (float)i1[r];
            if (b2[r] - b1[r] <= TAU) {
                int pos = atomicAdd(cnt, 1);
                if (pos < cap) list[pos] = tokW + q * 4 + r;
            }
        }
        *reinterpret_cast<float4*>(out + IND_OFF + tokW + q * 4) = iv;
    }
    double lsum = 0.0;
    #pragma unroll
    for (int r = 0; r < 4; ++r) {
        float z2r = __shfl(sq, (lane & 48) | (q * 4 + r), 64);
        if ((lane & 15) == 0) lsum += (double)z2r + (double)b1[r];
    }
    lsum += __shfl_xor(lsum, 16, 64);
    lsum += __shfl_xor(lsum, 32, 64);
    if (lane == 0) atomicAdd(loss_acc, lsum);

    // ---- gather z_q rows from codebook, write out ----
    float4* out4 = reinterpret_cast<float4*>(out);
    #pragma unroll
    for (int tt = 0; tt < 16; ++tt) {
        int code = __shfl(i1[tt & 3], (tt >> 2) * 16, 64);
        float4 cv = cb4[(size_t)code * 64 + lane];
        out4[(size_t)(tokW + tt) * 64 + lane] = cv;
    }
}

// ---------------------------------------------------------------------------
// FALLBACK (small ws): round-3 f32 VALU kernel, verified correct.
// ---------------------------------------------------------------------------
#define BM   128
#define NC   128
#define KS   32
#define PAD  33

__global__ void vq_init(const float* __restrict__ cb, float* __restrict__ c2,
                        double* __restrict__ acc, int* __restrict__ cnt) {
    int k = threadIdx.x;
    if (k == 0) { *acc = 0.0; *cnt = 0; }
    const float* row = cb + k * HID;
    double s = 0.0;
    for (int i = 0; i < HID; ++i) {
        double v = (double)row[i];
        s = fma(v, v, s);
    }
    c2[k] = (float)s;
}

__global__ __launch_bounds__(256, 2) void vq_main_f32(
    const float* __restrict__ z, const float* __restrict__ cb,
    const float* __restrict__ c2g, float* __restrict__ out,
    double* __restrict__ loss_acc, int* __restrict__ cnt,
    int* __restrict__ list, int cap) {

    __shared__ float smem[(BM + NC) * PAD];
    float* zs = smem;
    float* cs = smem + BM * PAD;

    const int tid = threadIdx.x;
    const int tx = tid & 15;
    const int ty = tid >> 4;
    const int tokBase = blockIdx.x * BM;

    const float4* z4g  = reinterpret_cast<const float4*>(z);
    const float4* cb4g = reinterpret_cast<const float4*>(cb);

    float bs[8], bs2[8];
    int   bi[8];
    #pragma unroll
    for (int m = 0; m < 8; ++m) { bs[m] = 3.4e38f; bs2[m] = 3.4e38f; bi[m] = 0; }

    for (int chunk = 0; chunk < KCODES / NC; ++chunk) {
        float acc[8][8];
        #pragma unroll
        for (int m = 0; m < 8; ++m)
            #pragma unroll
            for (int n = 0; n < 8; ++n) acc[m][n] = 0.f;

        for (int ks = 0; ks < HID / KS; ++ks) {
            __syncthreads();
            #pragma unroll
            for (int i = 0; i < 4; ++i) {
                int f   = tid + i * 256;
                int row = f >> 3;
                int k4  = f & 7;
                float4 zv = z4g[(tokBase + row) * (HID / 4) + ks * (KS / 4) + k4];
                int b = row * PAD + k4 * 4;
                zs[b + 0] = zv.x; zs[b + 1] = zv.y; zs[b + 2] = zv.z; zs[b + 3] = zv.w;
                float4 cv = cb4g[(chunk * NC + row) * (HID / 4) + ks * (KS / 4) + k4];
                cs[b + 0] = cv.x; cs[b + 1] = cv.y; cs[b + 2] = cv.z; cs[b + 3] = cv.w;
            }
            __syncthreads();

            #pragma unroll 2
            for (int k = 0; k < KS; ++k) {
                float zf[8], cf[8];
                #pragma unroll
                for (int m = 0; m < 8; ++m) zf[m] = zs[(ty * 8 + m) * PAD + k];
                #pragma unroll
                for (int n = 0; n < 8; ++n) cf[n] = cs[(tx * 8 + n) * PAD + k];
                #pragma unroll
                for (int m = 0; m < 8; ++m)
                    #pragma unroll
                    for (int n = 0; n < 8; ++n)
                        acc[m][n] = fmaf(zf[m], cf[n], acc[m][n]);
            }
        }

        #pragma unroll
        for (int n = 0; n < 8; ++n) {
            int code = chunk * NC + tx * 8 + n;
            float c2v = c2g[code];
            #pragma unroll
            for (int m = 0; m < 8; ++m) {
                float s = fmaf(-2.f, acc[m][n], c2v);
                if (s < bs[m]) { bs2[m] = bs[m]; bs[m] = s; bi[m] = code; }
                else if (s < bs2[m]) bs2[m] = s;
            }
        }
    }

    __syncthreads();
    float* rs   = smem;
    int*   ri   = reinterpret_cast<int*>(smem + BM * 16);
    float* rs2  = smem + BM * 32;
    int*   inds = reinterpret_cast<int*>(smem + BM * 48);
    float* wred = smem + BM * 48 + BM;

    #pragma unroll
    for (int m = 0; m < 8; ++m) {
        int tok = ty * 8 + m;
        rs [tok * 16 + tx] = bs[m];
        ri [tok * 16 + tx] = bi[m];
        rs2[tok * 16 + tx] = bs2[m];
    }
    __syncthreads();

    if (tid < BM) {
        float B1 = rs[tid * 16];
        int   I1 = ri[tid * 16];
        float B2 = rs2[tid * 16];
        for (int j = 1; j < 16; ++j) {
            float b1v = rs [tid * 16 + j];
            int   i1v = ri [tid * 16 + j];
            float b2v = rs2[tid * 16 + j];
            if (b1v < B1 || (b1v == B1 && i1v < I1)) {
                B2 = fminf(B1, b2v); B1 = b1v; I1 = i1v;
            } else {
                B2 = fminf(B2, b1v);
            }
        }
        inds[tid] = I1;
        out[IND_OFF + tokBase + tid] = (float)I1;
        if (B2 - B1 <= TAU) {
            int pos = atomicAdd(cnt, 1);
            if (pos < cap) list[pos] = tokBase + tid;
        }
    }
    __syncthreads();

    float loc = 0.f;
    float4* out4 = reinterpret_cast<float4*>(out);
    for (int it = 0; it < (BM * HID / 4) / 256; ++it) {
        int e4  = it * 256 + tid;
        int tok = e4 >> 6;
        int h4  = e4 & 63;
        int code = inds[tok];
        float4 cv = cb4g[code * 64 + h4];
        float4 zv = z4g[(tokBase + tok) * 64 + h4];
        out4[(tokBase + tok) * 64 + h4] = cv;
        float dx = cv.x - zv.x, dy = cv.y - zv.y;
        float dz = cv.z - zv.z, dw = cv.w - zv.w;
        loc = fmaf(dx, dx, loc);
        loc = fmaf(dy, dy, loc);
        loc = fmaf(dz, dz, loc);
        loc = fmaf(dw, dw, loc);
    }
    #pragma unroll
    for (int off = 32; off > 0; off >>= 1) loc += __shfl_xor(loc, off, 64);
    int wave = tid >> 6;
    if ((tid & 63) == 0) wred[wave] = loc;
    __syncthreads();
    if (tid == 0) {
        double t = (double)wred[0] + (double)wred[1] +
                   (double)wred[2] + (double)wred[3];
        atomicAdd(loss_acc, t);
    }
}

// ---------------------------------------------------------------------------
// refine: re-score flagged tokens with the EMULATED reference f32 pipeline:
//   D_k = fl32( fl32(z2 - fl32(2*cross_k)) + c2_k ),  argmin first-index.
// Also finalizes the loss output (block 0, thread 0).
// ---------------------------------------------------------------------------
__global__ __launch_bounds__(256) void vq_refine(
    const float* __restrict__ z, const float* __restrict__ cb,
    const float* __restrict__ c2g, const double* __restrict__ loss_acc,
    const int* __restrict__ cnt, const int* __restrict__ list,
    float* __restrict__ out, int cap) {

    if (blockIdx.x == 0 && threadIdx.x == 0)
        out[LOSS_OFF] = (float)(2.0 * (*loss_acc) / (double)(M_TOKENS * HID));

    __shared__ float  zrow[HID];
    __shared__ double red_d[256];
    __shared__ int    red_i[256];

    const int tid = threadIdx.x;
    int n = *cnt; if (n > cap) n = cap;

    for (int idx = blockIdx.x; idx < n; idx += gridDim.x) {
        int t = list[idx];
        float zi = z[t * HID + tid];
        zrow[tid] = zi;
        red_d[tid] = (double)zi * (double)zi;
        __syncthreads();
        for (int s = 128; s > 0; s >>= 1) {
            if (tid < s) red_d[tid] += red_d[tid + s];
            __syncthreads();
        }
        float z2f = (float)red_d[0];
        __syncthreads();

        double bestD = 1e300; int bestK = 1 << 30;
        #pragma unroll
        for (int c = 0; c < 2; ++c) {
            int k = tid + c * 256;
            const float* cr = cb + k * HID;
            double acc = 0.0;
            for (int i = 0; i < HID; ++i)
                acc = fma((double)zrow[i], (double)cr[i], acc);
            float cross32 = (float)acc;
            float u = 2.0f * cross32;
            float tq = (float)((double)z2f - (double)u);
            double v = (double)tq + (double)c2g[k];
            float D = (float)v;
            double Dd = (double)D;
            if (Dd < bestD || (Dd == bestD && k < bestK)) { bestD = Dd; bestK = k; }
        }
        red_d[tid] = bestD; red_i[tid] = bestK;
        __syncthreads();
        for (int s = 128; s > 0; s >>= 1) {
            if (tid < s) {
                double d2 = red_d[tid + s]; int i2 = red_i[tid + s];
                if (d2 < red_d[tid] || (d2 == red_d[tid] && i2 < red_i[tid])) {
                    red_d[tid] = d2; red_i[tid] = i2;
                }
            }
            __syncthreads();
        }
        int best = red_i[0];
        if (tid == 0) out[IND_OFF + t] = (float)best;
        out[t * HID + tid] = cb[best * HID + tid];
        __syncthreads();
    }
}

extern "C" void kernel_launch(void* const* d_in, const int* in_sizes, int n_in,
                              void* d_out, int out_size, void* d_ws, size_t ws_size,
                              hipStream_t stream) {
    const float* z  = (const float*)d_in[0];
    const float* cb = (const float*)d_in[1];
    float* out = (float*)d_out;
    double* acc = (double*)d_ws;
    int*  cnt = (int*)((char*)d_ws + 8);
    float* c2 = (float*)((char*)d_ws + WS_C2_OFF);

    if (ws_size >= WS_MIN_FAST) {
        unsigned short* Bhi = (unsigned short*)((char*)d_ws + WS_BHI_OFF);
        unsigned short* Blo = (unsigned short*)((char*)d_ws + WS_BLO_OFF);
        int* list = (int*)((char*)d_ws + WS_LIST_OFF_FAST);
        int cap = 8192;
        vq_prep<<<66, 256, 0, stream>>>(cb, Bhi, Blo, c2, acc, cnt);
        vq_main_mfma<<<M_TOKENS / 64, 256, 0, stream>>>(
            z, cb, c2, Bhi, Blo, out, acc, cnt, list, cap);
        vq_refine<<<512, 256, 0, stream>>>(z, cb, c2, acc, cnt, list, out, cap);
    } else {
        int* list = (int*)((char*)d_ws + WS_LIST_OFF_SLOW);
        int cap = 0;
        if (ws_size > WS_LIST_OFF_SLOW + 16) {
            size_t avail = (ws_size - WS_LIST_OFF_SLOW) / 4;
            cap = (avail > 8192) ? 8192 : (int)avail;
        }
        vq_init<<<1, 512, 0, stream>>>(cb, c2, acc, cnt);
        vq_main_f32<<<M_TOKENS / BM, 256, 0, stream>>>(
            z, cb, c2, out, acc, cnt, list, cap);
        vq_refine<<<512, 256, 0, stream>>>(z, cb, c2, acc, cnt, list, out, cap);
    }
}

// Round 6
// 175.412 us; speedup vs baseline: 2.4921x; 1.3143x over previous
//
#include <hip/hip_runtime.h>

// Problem constants
#define M_TOKENS 65536      // 8 * 8192
#define HID      256
#define KCODES   512

#define IND_OFF  (M_TOKENS * HID)          // 16777216
#define LOSS_OFF (IND_OFF + M_TOKENS)      // 16842752

// Flag threshold: any token whose top-2 score gap is below this gets exact
// re-scoring with the emulated reference-f32 quantization pipeline.
// bf16-split GEMM worst-case score error ~5e-6 << TAU; grid 2*3.05e-5 < TAU.
#define TAU      1.5e-4f

// ws layout (fast path):
//   [0:8) double loss | [8:12) int cnt | [16:2064) c2[512]
//   [4096 : +256K) B_hi fragments | [266240 : +256K) B_lo | [528384 : +32K) list
#define WS_C2_OFF        16
#define WS_BHI_OFF       4096
#define WS_BLO_OFF       (4096 + 262144)
#define WS_LIST_OFF_FAST (4096 + 524288)
#define WS_LIST_OFF_SLOW 4096
#define WS_MIN_FAST      (WS_LIST_OFF_FAST + 8192 * 4)

typedef __attribute__((ext_vector_type(8))) short  short8;   // 8 bf16
typedef __attribute__((ext_vector_type(4))) float  f32x4;

__device__ inline unsigned short f2bf(float f) {             // RNE f32->bf16
    unsigned u = __float_as_uint(f);
    u += 0x7FFF + ((u >> 16) & 1);
    return (unsigned short)(u >> 16);
}
__device__ inline float bf2f(unsigned short h) {
    return __uint_as_float(((unsigned)h) << 16);
}

// ---------------------------------------------------------------------------
// prep: blocks 0..63 swizzle codebook into MFMA B-fragment order (bf16 hi/lo);
//       blocks 64..65 compute c2[k] (f64) and zero the accumulators.
// Fragment (nb, kb): lane l, elem j -> code = nb*16 + (l&15),
//                                      k = kb*32 + (l>>4)*8 + j.
// ---------------------------------------------------------------------------
__global__ __launch_bounds__(256) void vq_prep(
    const float* __restrict__ cb,
    unsigned short* __restrict__ Bhi, unsigned short* __restrict__ Blo,
    float* __restrict__ c2, double* __restrict__ acc, int* __restrict__ cnt) {
    int b = blockIdx.x;
    if (b < 64) {
        int g = b * 256 + threadIdx.x;   // 0..16383 = frag*64 + lane
        int frag = g >> 6, lane = g & 63;
        int nb = frag >> 3, kb = frag & 7;
        int code = nb * 16 + (lane & 15);
        int kk = kb * 32 + (lane >> 4) * 8;
        const float4* s4 = reinterpret_cast<const float4*>(cb + code * HID + kk);
        float4 v0 = s4[0], v1 = s4[1];
        float f[8] = {v0.x, v0.y, v0.z, v0.w, v1.x, v1.y, v1.z, v1.w};
        short8 vh, vl;
        #pragma unroll
        for (int j = 0; j < 8; ++j) {
            unsigned short h = f2bf(f[j]);
            vh[j] = (short)h;
            vl[j] = (short)f2bf(f[j] - bf2f(h));
        }
        *reinterpret_cast<short8*>(Bhi + (size_t)g * 8) = vh;
        *reinterpret_cast<short8*>(Blo + (size_t)g * 8) = vl;
    } else {
        if (b == 64 && threadIdx.x == 0) { *acc = 0.0; *cnt = 0; }
        int k = (b - 64) * 256 + threadIdx.x;   // 0..511
        const float* row = cb + k * HID;
        double s = 0.0;
        for (int i = 0; i < HID; ++i) {
            double v = (double)row[i];
            s = fma(v, v, s);
        }
        c2[k] = (float)s;
    }
}

// ---------------------------------------------------------------------------
// main MFMA kernel: bf16-split cross-term + top-2 argmin + gather + loss.
// 256 threads = 4 waves; wave owns 32 tokens (2 M-frags). Grid = 512 blocks
// (2 blocks/CU). B staged per 16-code chunk into double-buffered LDS via
// global_load_lds (width 16), T3 2-phase: stage(nb+1) issued before
// compute(nb), one barrier per chunk. Loss algebraic (no z re-read).
// ---------------------------------------------------------------------------
__global__ __launch_bounds__(256, 2) void vq_main_mfma(
    const float* __restrict__ z, const float* __restrict__ cb,
    const float* __restrict__ c2g,
    const unsigned short* __restrict__ Bhi,
    const unsigned short* __restrict__ Blo,
    float* __restrict__ out, double* __restrict__ loss_acc,
    int* __restrict__ cnt, int* __restrict__ list, int cap) {

    __shared__ short8 ldsB[2][16][64];   // [buf][frag: 0..7 hi, 8..15 lo][lane]
    __shared__ float  lds_c2[KCODES];    // 2 KB

    const int tid  = threadIdx.x;
    const int wid  = tid >> 6;
    const int lane = tid & 63;
    const int q    = lane >> 4;
    const int tokW = blockIdx.x * 128 + wid * 32;   // wave's first token

    const float4* z4  = reinterpret_cast<const float4*>(z);
    const float4* cb4 = reinterpret_cast<const float4*>(cb);

    // stage c2 into LDS (covered by the prologue barrier)
    lds_c2[tid]       = c2g[tid];
    lds_c2[tid + 256] = c2g[tid + 256];

    // stage one 16-frag chunk (16 KB): wave wid loads frags wid*4..wid*4+3
#define STAGE(nbv, bufv) do {                                                  \
        _Pragma("unroll")                                                      \
        for (int j = 0; j < 4; ++j) {                                          \
            int f_  = (wid << 2) | j;                                          \
            int kb_ = f_ & 7;                                                  \
            const unsigned short* src_ =                                       \
                ((f_ < 8) ? Bhi : Blo) +                                       \
                (((size_t)((nbv) * 8 + kb_) * 64 + lane) << 3);                \
            __builtin_amdgcn_global_load_lds(                                  \
                (const __attribute__((address_space(1))) void*)src_,           \
                (__attribute__((address_space(3))) void*)&ldsB[bufv][f_][0],   \
                16, 0, 0);                                                     \
        }                                                                      \
    } while (0)

    // ---- load wave's 32 z rows as A fragments (bf16 hi/lo) + z2 ----
    // A frag (mf,kb): lane holds token tokW+mf*16+(l&15), k = kb*32+(l>>4)*8+j
    short8 ah[2][8], al[2][8];
    float sq[2];
    #pragma unroll
    for (int mf = 0; mf < 2; ++mf) {
        int token = tokW + mf * 16 + (lane & 15);
        const float4* zr = z4 + (size_t)token * 64 + q * 2;
        float s = 0.f;
        #pragma unroll
        for (int kb = 0; kb < 8; ++kb) {
            float4 v0 = zr[kb * 8];
            float4 v1 = zr[kb * 8 + 1];
            float f[8] = {v0.x, v0.y, v0.z, v0.w, v1.x, v1.y, v1.z, v1.w};
            short8 vh, vl;
            #pragma unroll
            for (int j = 0; j < 8; ++j) {
                unsigned short h = f2bf(f[j]);
                vh[j] = (short)h;
                vl[j] = (short)f2bf(f[j] - bf2f(h));
                s = fmaf(f[j], f[j], s);
            }
            ah[mf][kb] = vh;
            al[mf][kb] = vl;
        }
        // z2 of token tokW+mf*16+(lane&15), replicated across q-groups
        s += __shfl_xor(s, 16, 64);
        s += __shfl_xor(s, 32, 64);
        sq[mf] = s;
    }

    // prologue: stage chunk 0; barrier drains vmcnt + orders lds_c2
    STAGE(0, 0);
    __syncthreads();

    // per-lane running top-2 for 2 mfrags x 4 rows
    float b1[2][4], b2[2][4];
    int   i1[2][4];
    #pragma unroll
    for (int mf = 0; mf < 2; ++mf)
        #pragma unroll
        for (int r = 0; r < 4; ++r) { b1[mf][r] = 3.4e38f; b2[mf][r] = 3.4e38f; i1[mf][r] = 0; }

    // ---- main loop over 32 code-chunks of 16 ----
    for (int nb = 0; nb < 32; ++nb) {
        int buf = nb & 1;
        if (nb < 31) STAGE(nb + 1, buf ^ 1);   // async prefetch, overlaps MFMAs

        f32x4 a0 = {0.f, 0.f, 0.f, 0.f};
        f32x4 a1 = {0.f, 0.f, 0.f, 0.f};
        #pragma unroll
        for (int kb = 0; kb < 8; ++kb) {
            short8 vbh = ldsB[buf][kb][lane];
            short8 vbl = ldsB[buf][8 + kb][lane];
            a0 = __builtin_amdgcn_mfma_f32_16x16x32_bf16(ah[0][kb], vbh, a0, 0, 0, 0);
            a1 = __builtin_amdgcn_mfma_f32_16x16x32_bf16(ah[1][kb], vbh, a1, 0, 0, 0);
            a0 = __builtin_amdgcn_mfma_f32_16x16x32_bf16(al[0][kb], vbh, a0, 0, 0, 0);
            a1 = __builtin_amdgcn_mfma_f32_16x16x32_bf16(al[1][kb], vbh, a1, 0, 0, 0);
            a0 = __builtin_amdgcn_mfma_f32_16x16x32_bf16(ah[0][kb], vbl, a0, 0, 0, 0);
            a1 = __builtin_amdgcn_mfma_f32_16x16x32_bf16(ah[1][kb], vbl, a1, 0, 0, 0);
        }
        int code = nb * 16 + (lane & 15);
        float c2v = lds_c2[code];
        #pragma unroll
        for (int r = 0; r < 4; ++r) {
            float s0 = fmaf(-2.f, a0[r], c2v);   // c2 - 2*cross
            if (s0 < b1[0][r]) { b2[0][r] = b1[0][r]; b1[0][r] = s0; i1[0][r] = code; }
            else if (s0 < b2[0][r]) b2[0][r] = s0;
            float s1 = fmaf(-2.f, a1[r], c2v);
            if (s1 < b1[1][r]) { b2[1][r] = b1[1][r]; b1[1][r] = s1; i1[1][r] = code; }
            else if (s1 < b2[1][r]) b2[1][r] = s1;
        }
        __syncthreads();   // drains stage(nb+1) + all waves done with buf
    }
#undef STAGE

    // ---- merge top-2 across the 16 lanes of each row group ----
    #pragma unroll
    for (int st = 1; st <= 8; st <<= 1) {
        #pragma unroll
        for (int mf = 0; mf < 2; ++mf)
            #pragma unroll
            for (int r = 0; r < 4; ++r) {
                float ob1 = __shfl_xor(b1[mf][r], st, 64);
                int   oi1 = __shfl_xor(i1[mf][r], st, 64);
                float ob2 = __shfl_xor(b2[mf][r], st, 64);
                if (ob1 < b1[mf][r] || (ob1 == b1[mf][r] && oi1 < i1[mf][r])) {
                    b2[mf][r] = fminf(b1[mf][r], ob2);
                    b1[mf][r] = ob1;
                    i1[mf][r] = oi1;
                } else {
                    b2[mf][r] = fminf(b2[mf][r], ob1);
                }
            }
    }

    // ---- indices + ambiguity flags ----
    if ((lane & 15) == 0) {
        #pragma unroll
        for (int mf = 0; mf < 2; ++mf) {
            float4 iv;
            #pragma unroll
            for (int r = 0; r < 4; ++r) {
                ((float*)&iv)[r] = (float)i1[mf][r];
                if (b2[mf][r] - b1[mf][r] <= TAU) {
                    int pos = atomicAdd(cnt, 1);
                    if (pos < cap) list[pos] = tokW + mf * 16 + q * 4 + r;
                }
            }
            *reinterpret_cast<float4*>(out + IND_OFF + tokW + mf * 16 + q * 4) = iv;
        }
    }

    // ---- loss: ||zq-z||^2 = z2 + (c2_best - 2 cross_best) = z2 + b1 ----
    double lsum = 0.0;
    #pragma unroll
    for (int mf = 0; mf < 2; ++mf)
        #pragma unroll
        for (int r = 0; r < 4; ++r) {
            float z2r = __shfl(sq[mf], (lane & 48) | (q * 4 + r), 64);
            if ((lane & 15) == 0) lsum += (double)z2r + (double)b1[mf][r];
        }
    lsum += __shfl_xor(lsum, 16, 64);
    lsum += __shfl_xor(lsum, 32, 64);
    if (lane == 0) atomicAdd(loss_acc, lsum);

    // ---- gather z_q rows from codebook, write out ----
    float4* out4 = reinterpret_cast<float4*>(out);
    #pragma unroll
    for (int tt = 0; tt < 32; ++tt) {
        int code = __shfl(i1[tt >> 4][tt & 3], ((tt >> 2) & 3) * 16, 64);
        float4 cv = cb4[(size_t)code * 64 + lane];
        out4[(size_t)(tokW + tt) * 64 + lane] = cv;
    }
}

// ---------------------------------------------------------------------------
// FALLBACK (small ws): round-3 f32 VALU kernel, verified correct.
// ---------------------------------------------------------------------------
#define BM   128
#define NC   128
#define KS   32
#define PAD  33

__global__ void vq_init(const float* __restrict__ cb, float* __restrict__ c2,
                        double* __restrict__ acc, int* __restrict__ cnt) {
    int k = threadIdx.x;
    if (k == 0) { *acc = 0.0; *cnt = 0; }
    const float* row = cb + k * HID;
    double s = 0.0;
    for (int i = 0; i < HID; ++i) {
        double v = (double)row[i];
        s = fma(v, v, s);
    }
    c2[k] = (float)s;
}

__global__ __launch_bounds__(256, 2) void vq_main_f32(
    const float* __restrict__ z, const float* __restrict__ cb,
    const float* __restrict__ c2g, float* __restrict__ out,
    double* __restrict__ loss_acc, int* __restrict__ cnt,
    int* __restrict__ list, int cap) {

    __shared__ float smem[(BM + NC) * PAD];
    float* zs = smem;
    float* cs = smem + BM * PAD;

    const int tid = threadIdx.x;
    const int tx = tid & 15;
    const int ty = tid >> 4;
    const int tokBase = blockIdx.x * BM;

    const float4* z4g  = reinterpret_cast<const float4*>(z);
    const float4* cb4g = reinterpret_cast<const float4*>(cb);

    float bs[8], bs2[8];
    int   bi[8];
    #pragma unroll
    for (int m = 0; m < 8; ++m) { bs[m] = 3.4e38f; bs2[m] = 3.4e38f; bi[m] = 0; }

    for (int chunk = 0; chunk < KCODES / NC; ++chunk) {
        float acc[8][8];
        #pragma unroll
        for (int m = 0; m < 8; ++m)
            #pragma unroll
            for (int n = 0; n < 8; ++n) acc[m][n] = 0.f;

        for (int ks = 0; ks < HID / KS; ++ks) {
            __syncthreads();
            #pragma unroll
            for (int i = 0; i < 4; ++i) {
                int f   = tid + i * 256;
                int row = f >> 3;
                int k4  = f & 7;
                float4 zv = z4g[(tokBase + row) * (HID / 4) + ks * (KS / 4) + k4];
                int b = row * PAD + k4 * 4;
                zs[b + 0] = zv.x; zs[b + 1] = zv.y; zs[b + 2] = zv.z; zs[b + 3] = zv.w;
                float4 cv = cb4g[(chunk * NC + row) * (HID / 4) + ks * (KS / 4) + k4];
                cs[b + 0] = cv.x; cs[b + 1] = cv.y; cs[b + 2] = cv.z; cs[b + 3] = cv.w;
            }
            __syncthreads();

            #pragma unroll 2
            for (int k = 0; k < KS; ++k) {
                float zf[8], cf[8];
                #pragma unroll
                for (int m = 0; m < 8; ++m) zf[m] = zs[(ty * 8 + m) * PAD + k];
                #pragma unroll
                for (int n = 0; n < 8; ++n) cf[n] = cs[(tx * 8 + n) * PAD + k];
                #pragma unroll
                for (int m = 0; m < 8; ++m)
                    #pragma unroll
                    for (int n = 0; n < 8; ++n)
                        acc[m][n] = fmaf(zf[m], cf[n], acc[m][n]);
            }
        }

        #pragma unroll
        for (int n = 0; n < 8; ++n) {
            int code = chunk * NC + tx * 8 + n;
            float c2v = c2g[code];
            #pragma unroll
            for (int m = 0; m < 8; ++m) {
                float s = fmaf(-2.f, acc[m][n], c2v);
                if (s < bs[m]) { bs2[m] = bs[m]; bs[m] = s; bi[m] = code; }
                else if (s < bs2[m]) bs2[m] = s;
            }
        }
    }

    __syncthreads();
    float* rs   = smem;
    int*   ri   = reinterpret_cast<int*>(smem + BM * 16);
    float* rs2  = smem + BM * 32;
    int*   inds = reinterpret_cast<int*>(smem + BM * 48);
    float* wred = smem + BM * 48 + BM;

    #pragma unroll
    for (int m = 0; m < 8; ++m) {
        int tok = ty * 8 + m;
        rs [tok * 16 + tx] = bs[m];
        ri [tok * 16 + tx] = bi[m];
        rs2[tok * 16 + tx] = bs2[m];
    }
    __syncthreads();

    if (tid < BM) {
        float B1 = rs[tid * 16];
        int   I1 = ri[tid * 16];
        float B2 = rs2[tid * 16];
        for (int j = 1; j < 16; ++j) {
            float b1v = rs [tid * 16 + j];
            int   i1v = ri [tid * 16 + j];
            float b2v = rs2[tid * 16 + j];
            if (b1v < B1 || (b1v == B1 && i1v < I1)) {
                B2 = fminf(B1, b2v); B1 = b1v; I1 = i1v;
            } else {
                B2 = fminf(B2, b1v);
            }
        }
        inds[tid] = I1;
        out[IND_OFF + tokBase + tid] = (float)I1;
        if (B2 - B1 <= TAU) {
            int pos = atomicAdd(cnt, 1);
            if (pos < cap) list[pos] = tokBase + tid;
        }
    }
    __syncthreads();

    float loc = 0.f;
    float4* out4 = reinterpret_cast<float4*>(out);
    for (int it = 0; it < (BM * HID / 4) / 256; ++it) {
        int e4  = it * 256 + tid;
        int tok = e4 >> 6;
        int h4  = e4 & 63;
        int code = inds[tok];
        float4 cv = cb4g[code * 64 + h4];
        float4 zv = z4g[(tokBase + tok) * 64 + h4];
        out4[(tokBase + tok) * 64 + h4] = cv;
        float dx = cv.x - zv.x, dy = cv.y - zv.y;
        float dz = cv.z - zv.z, dw = cv.w - zv.w;
        loc = fmaf(dx, dx, loc);
        loc = fmaf(dy, dy, loc);
        loc = fmaf(dz, dz, loc);
        loc = fmaf(dw, dw, loc);
    }
    #pragma unroll
    for (int off = 32; off > 0; off >>= 1) loc += __shfl_xor(loc, off, 64);
    int wave = tid >> 6;
    if ((tid & 63) == 0) wred[wave] = loc;
    __syncthreads();
    if (tid == 0) {
        double t = (double)wred[0] + (double)wred[1] +
                   (double)wred[2] + (double)wred[3];
        atomicAdd(loss_acc, t);
    }
}

// ---------------------------------------------------------------------------
// refine: re-score flagged tokens with the EMULATED reference f32 pipeline:
//   D_k = fl32( fl32(z2 - fl32(2*cross_k)) + c2_k ),  argmin first-index.
// Also finalizes the loss output (block 0, thread 0).
// ---------------------------------------------------------------------------
__global__ __launch_bounds__(256) void vq_refine(
    const float* __restrict__ z, const float* __restrict__ cb,
    const float* __restrict__ c2g, const double* __restrict__ loss_acc,
    const int* __restrict__ cnt, const int* __restrict__ list,
    float* __restrict__ out, int cap) {

    if (blockIdx.x == 0 && threadIdx.x == 0)
        out[LOSS_OFF] = (float)(2.0 * (*loss_acc) / (double)(M_TOKENS * HID));

    __shared__ float  zrow[HID];
    __shared__ double red_d[256];
    __shared__ int    red_i[256];

    const int tid = threadIdx.x;
    int n = *cnt; if (n > cap) n = cap;

    for (int idx = blockIdx.x; idx < n; idx += gridDim.x) {
        int t = list[idx];
        float zi = z[t * HID + tid];
        zrow[tid] = zi;
        red_d[tid] = (double)zi * (double)zi;
        __syncthreads();
        for (int s = 128; s > 0; s >>= 1) {
            if (tid < s) red_d[tid] += red_d[tid + s];
            __syncthreads();
        }
        float z2f = (float)red_d[0];
        __syncthreads();

        double bestD = 1e300; int bestK = 1 << 30;
        #pragma unroll
        for (int c = 0; c < 2; ++c) {
            int k = tid + c * 256;
            const float* cr = cb + k * HID;
            double acc = 0.0;
            for (int i = 0; i < HID; ++i)
                acc = fma((double)zrow[i], (double)cr[i], acc);
            float cross32 = (float)acc;
            float u = 2.0f * cross32;
            float tq = (float)((double)z2f - (double)u);
            double v = (double)tq + (double)c2g[k];
            float D = (float)v;
            double Dd = (double)D;
            if (Dd < bestD || (Dd == bestD && k < bestK)) { bestD = Dd; bestK = k; }
        }
        red_d[tid] = bestD; red_i[tid] = bestK;
        __syncthreads();
        for (int s = 128; s > 0; s >>= 1) {
            if (tid < s) {
                double d2 = red_d[tid + s]; int i2 = red_i[tid + s];
                if (d2 < red_d[tid] || (d2 == red_d[tid] && i2 < red_i[tid])) {
                    red_d[tid] = d2; red_i[tid] = i2;
                }
            }
            __syncthreads();
        }
        int best = red_i[0];
        if (tid == 0) out[IND_OFF + t] = (float)best;
        out[t * HID + tid] = cb[best * HID + tid];
        __syncthreads();
    }
}

extern "C" void kernel_launch(void* const* d_in, const int* in_sizes, int n_in,
                              void* d_out, int out_size, void* d_ws, size_t ws_size,
                              hipStream_t stream) {
    const float* z  = (const float*)d_in[0];
    const float* cb = (const float*)d_in[1];
    float* out = (float*)d_out;
    double* acc = (double*)d_ws;
    int*  cnt = (int*)((char*)d_ws + 8);
    float* c2 = (float*)((char*)d_ws + WS_C2_OFF);

    if (ws_size >= WS_MIN_FAST) {
        unsigned short* Bhi = (unsigned short*)((char*)d_ws + WS_BHI_OFF);
        unsigned short* Blo = (unsigned short*)((char*)d_ws + WS_BLO_OFF);
        int* list = (int*)((char*)d_ws + WS_LIST_OFF_FAST);
        int cap = 8192;
        vq_prep<<<66, 256, 0, stream>>>(cb, Bhi, Blo, c2, acc, cnt);
        vq_main_mfma<<<M_TOKENS / 128, 256, 0, stream>>>(
            z, cb, c2, Bhi, Blo, out, acc, cnt, list, cap);
        vq_refine<<<512, 256, 0, stream>>>(z, cb, c2, acc, cnt, list, out, cap);
    } else {
        int* list = (int*)((char*)d_ws + WS_LIST_OFF_SLOW);
        int cap = 0;
        if (ws_size > WS_LIST_OFF_SLOW + 16) {
            size_t avail = (ws_size - WS_LIST_OFF_SLOW) / 4;
            cap = (avail > 8192) ? 8192 : (int)avail;
        }
        vq_init<<<1, 512, 0, stream>>>(cb, c2, acc, cnt);
        vq_main_f32<<<M_TOKENS / BM, 256, 0, stream>>>(
            z, cb, c2, out, acc, cnt, list, cap);
        vq_refine<<<512, 256, 0, stream>>>(z, cb, c2, acc, cnt, list, out, cap);
    }
}